// Round 4
// baseline (145.756 us; speedup 1.0000x reference)
//
#include <hip/hip_runtime.h>
#include <math.h>

// Problem constants (from reference setup_inputs)
#define BB 32
#define CC 512
#define HH 64
#define WW 64
#define RR 16
#define CR (CC / RR)      // 32
#define BPG 16            // batches per group (16 * 8 MB = 128 MB chunk, fits 256 MB L3)
#define NGROUPS (BB / BPG)

typedef float floatx4 __attribute__((ext_vector_type(4)));

__device__ __forceinline__ float wave_sum64(float v) {
    #pragma unroll
    for (int off = 32; off > 0; off >>= 1)
        v += __shfl_xor(v, off, 64);
    return v;
}

// --- Squeeze (fused gauss): squeezed[b][c] = sum_{h,w} x[b,c,h,w]*kx[b,h]*ky[b,w]
// grid = (C/4, BPG), block = 256 (4 waves); wave wv handles channel bx*4+wv.
// Reads this group's 128 MB chunk of x, leaving it resident in L3.
__global__ void k_squeeze(const float* __restrict__ x,
                          const float* __restrict__ mu,
                          const float* __restrict__ log_sigma,
                          float* __restrict__ sq, int b0) {
    __shared__ float s_kx[64];
    __shared__ float s_ky[64];
    int b = b0 + blockIdx.y;
    int tid = threadIdx.x;

    if (tid < 64) {
        float sigma = expf(log_sigma[0]);
        float inv2s = 1.0f / (2.0f * sigma);
        float g = (float)tid / 63.0f;       // linspace(0,1,64)
        float dh = g - mu[b * 2 + 0];       // grid_x varies along h -> mu[:,0]
        float dw = g - mu[b * 2 + 1];       // grid_y varies along w -> mu[:,1]
        float vx = expf(-dh * dh * inv2s);
        float vy = expf(-dw * dw * inv2s);
        float sx = wave_sum64(vx);
        float sy = wave_sum64(vy);
        s_kx[tid] = vx / sx;
        s_ky[tid] = vy / sy;
    }
    __syncthreads();

    int wv = tid >> 6;
    int lane = tid & 63;
    int c = blockIdx.x * 4 + wv;
    const floatx4* xp = (const floatx4*)(x + ((size_t)(b * CC + c)) * (HH * WW));
    int col = lane & 15;           // which float4 within a row (w0 = col*4)
    int hbase = lane >> 4;         // 0..3
    float a0 = 0.f, a1 = 0.f, a2 = 0.f, a3 = 0.f;
    #pragma unroll
    for (int it = 0; it < 16; ++it) {
        int h = hbase + it * 4;    // 64 lanes cover 4 full rows (1 KiB contiguous)
        floatx4 v = xp[h * 16 + col];
        float kh = s_kx[h];
        a0 += v.x * kh; a1 += v.y * kh; a2 += v.z * kh; a3 += v.w * kh;
    }
    int w0 = col * 4;
    float partial = a0 * s_ky[w0] + a1 * s_ky[w0 + 1] + a2 * s_ky[w0 + 2] + a3 * s_ky[w0 + 3];
    float s = wave_sum64(partial);
    if (lane == 0) sq[b * CC + c] = s;
}

// --- Fused MLP + scale: each block recomputes hid[b] (tiny), derives the
// sigmoid weights for its 8 channels, then streams out = x * w.
// grid = (64, BPG), block = 256. Re-reads the group's x chunk (L3-hot),
// writes out with non-temporal stores (no L3 pollution).
__global__ void k_scale_fused(const float* __restrict__ x,
                              const float* __restrict__ sq,
                              const float* __restrict__ w1,   // (CR, C)
                              const float* __restrict__ w2,   // (C, CR)
                              float* __restrict__ out, int b0) {
    __shared__ float s_sq[CC];
    __shared__ float s_hid[CR];
    __shared__ float s_w[8];
    int b = b0 + blockIdx.y;
    int c0 = blockIdx.x * 8;
    int tid = threadIdx.x;

    for (int i = tid; i < CC; i += 256) s_sq[i] = sq[b * CC + i];
    __syncthreads();

    // hid[j] = relu(w1[j,:] . sq[b,:]) ; 256 threads = 32 j x 8 segments of 64
    {
        int j = tid >> 3;
        int seg = tid & 7;
        float acc = 0.f;
        const float* w1r = w1 + j * CC + seg * 64;
        const float* sqr = s_sq + seg * 64;
        #pragma unroll 8
        for (int c = 0; c < 64; ++c) acc += sqr[c] * w1r[c];
        acc += __shfl_xor(acc, 4, 64);
        acc += __shfl_xor(acc, 2, 64);
        acc += __shfl_xor(acc, 1, 64);
        if (seg == 0) s_hid[j] = fmaxf(acc, 0.0f);
    }
    __syncthreads();

    // weights for this block's 8 channels
    if (tid < 8) {
        const float* w2r = w2 + (c0 + tid) * CR;
        float a = 0.f;
        #pragma unroll
        for (int jj = 0; jj < CR; ++jj) a += s_hid[jj] * w2r[jj];
        s_w[tid] = 1.0f / (1.0f + expf(-a));
    }
    __syncthreads();

    // stream 8 channels x 4096 floats = 8192 float4; 256 threads -> 32 iters
    const floatx4* xp = (const floatx4*)(x + ((size_t)(b * CC + c0)) * (HH * WW));
    floatx4* op = (floatx4*)(out + ((size_t)(b * CC + c0)) * (HH * WW));
    #pragma unroll 8
    for (int it = 0; it < 32; ++it) {
        int idx = it * 256 + tid;
        float s = s_w[idx >> 10];          // 1024 float4 per channel
        floatx4 v = xp[idx];
        __builtin_nontemporal_store(v * s, op + idx);
    }
}

extern "C" void kernel_launch(void* const* d_in, const int* in_sizes, int n_in,
                              void* d_out, int out_size, void* d_ws, size_t ws_size,
                              hipStream_t stream) {
    const float* x  = (const float*)d_in[0];
    const float* mu = (const float*)d_in[1];
    const float* ls = (const float*)d_in[2];
    const float* w1 = (const float*)d_in[3];
    const float* w2 = (const float*)d_in[4];
    float* out = (float*)d_out;

    float* sq = (float*)d_ws;       // B*C = 16384 floats

    for (int g = 0; g < NGROUPS; ++g) {
        int b0 = g * BPG;
        k_squeeze<<<dim3(CC / 4, BPG), 256, 0, stream>>>(x, mu, ls, sq, b0);
        k_scale_fused<<<dim3(64, BPG), 256, 0, stream>>>(x, sq, w1, w2, out, b0);
    }
}